// Round 7
// baseline (323.536 us; speedup 1.0000x reference)
//
#include <hip/hip_runtime.h>

typedef __bf16 bf16;
typedef __attribute__((ext_vector_type(8))) __bf16 bf16x8;
typedef __attribute__((ext_vector_type(4))) float f32x4;
typedef __attribute__((ext_vector_type(4))) short s16x4;

#define HDIM 2048

__device__ __forceinline__ void glds16(const void* g, void* l) {
  __builtin_amdgcn_global_load_lds((const __attribute__((address_space(1))) void*)g,
                                   (__attribute__((address_space(3))) void*)l,
                                   16, 0, 0);
}

#define MFMA16(a, b, c) __builtin_amdgcn_mfma_f32_16x16x32_bf16(a, b, c, 0, 0, 0)

// fp32 -> bf16 bulk convert: grid (1024, 5).
__global__ __launch_bounds__(256) void cvt5(
    const float* __restrict__ s0, const float* __restrict__ s1,
    const float* __restrict__ s2, const float* __restrict__ s3,
    const float* __restrict__ s4,
    bf16* __restrict__ d0, bf16* __restrict__ d1, bf16* __restrict__ d2,
    bf16* __restrict__ d3, bf16* __restrict__ d4) {
  const float* s; bf16* d;
  switch (blockIdx.y) {
    case 0: s = s0; d = d0; break;
    case 1: s = s1; d = d1; break;
    case 2: s = s2; d = d2; break;
    case 3: s = s3; d = d3; break;
    default: s = s4; d = d4; break;
  }
  const size_t base = (size_t)blockIdx.x * 4096 + (threadIdx.x << 2);
  for (int i = 0; i < 4; i++) {
    const float4 v = *(const float4*)(s + base + i * 1024);
    union { bf16 h[4]; s16x4 s4v; } u;
    u.h[0] = (bf16)v.x; u.h[1] = (bf16)v.y; u.h[2] = (bf16)v.z; u.h[3] = (bf16)v.w;
    *(s16x4*)(d + base + i * 1024) = u.s4v;
  }
}

// acc[4][4] = A[rowBase:+128, :] @ B[colBase:+128, :]^T, bf16 row-major.
// Frag-major LDS: each 16x32 MFMA fragment contiguous (1KB). glds16 source
// addresses permuted so LDS lands frag-major -> conflict-free ds_read_b128.
__device__ __forceinline__ void gemm128_core(const bf16* __restrict__ A,
                                             const bf16* __restrict__ B,
                                             int rowBase, int colBase,
                                             f32x4 acc[4][4],
                                             bf16* ldsA, bf16* ldsB) {
  const int t = threadIdx.x;
  const int w = t >> 6, l = t & 63;

  for (int mi = 0; mi < 4; mi++)
    for (int ni = 0; ni < 4; ni++)
      for (int r = 0; r < 4; r++) acc[mi][ni][r] = 0.f;

  // staging: wave w stages frags 2w, 2w+1 of A and of B.
  // lane l covers frag element: row = frag*16 + (l&15), k = (l>>4)*8..+8
  const int fr = l & 15;
  const int fc = (l >> 4) << 3;
  const bf16* gA0 = A + (size_t)(rowBase + w * 32 + fr) * HDIM + fc;
  const bf16* gA1 = gA0 + (size_t)16 * HDIM;
  const bf16* gB0 = B + (size_t)(colBase + w * 32 + fr) * HDIM + fc;
  const bf16* gB1 = gB0 + (size_t)16 * HDIM;
  bf16* lA = ldsA + (w << 10);
  bf16* lB = ldsB + (w << 10);

  const int af0 = (w >> 1) << 2;   // wave's A frag base (row offset /16)
  const int bf0 = (w & 1) << 2;    // wave's B frag base

  for (int k0 = 0; k0 < HDIM; k0 += 32) {
    glds16(gA0, lA);
    glds16(gA1, lA + 512);
    glds16(gB0, lB);
    glds16(gB1, lB + 512);
    gA0 += 32; gA1 += 32; gB0 += 32; gB1 += 32;
    __syncthreads();

    bf16x8 af[4], bfr[4];
    for (int mi = 0; mi < 4; mi++)
      af[mi] = *(const bf16x8*)&ldsA[(af0 + mi) * 512 + l * 8];
    for (int ni = 0; ni < 4; ni++)
      bfr[ni] = *(const bf16x8*)&ldsB[(bf0 + ni) * 512 + l * 8];
    for (int mi = 0; mi < 4; mi++)
      for (int ni = 0; ni < 4; ni++)
        acc[mi][ni] = MFMA16(af[mi], bfr[ni], acc[mi][ni]);
    __syncthreads();
  }
}

// z=0: q = hs@Wq^T (normal [B,H])
// z=1: Kf frag-major: frag ((h*16+kbk)*32 + ni*4+ks):
//      key = kbk*128+ni*16+(lane&15), dim = h*128+ks*32+(lane>>4)*8+j
// z=2: Vf frag-major: dim = h*128+ni*16+(lane&15), key = kbk*128+ks*32+(lane>>4)*8+j
__global__ __launch_bounds__(256) void qkv_gemm(
    const bf16* __restrict__ hs, const bf16* __restrict__ Wq,
    const bf16* __restrict__ Wk, const bf16* __restrict__ Wv,
    bf16* __restrict__ qb, bf16* __restrict__ Kf, bf16* __restrict__ Vf) {
  __shared__ bf16 ldsA[128 * 32];
  __shared__ bf16 ldsB[128 * 32];
  const int z = blockIdx.z;
  const bf16* W = (z == 0) ? Wq : (z == 1) ? Wk : Wv;
  const int rowBase = blockIdx.y << 7, colBase = blockIdx.x << 7;
  f32x4 acc[4][4];
  gemm128_core(hs, W, rowBase, colBase, acc, ldsA, ldsB);

  const int t = threadIdx.x;
  const int w = t >> 6, l = t & 63;
  const int wr = (w >> 1) << 6, wc = (w & 1) << 6;
  const int lr = l & 15, lq = l >> 4;

  if (z == 0) {
    for (int mi = 0; mi < 4; mi++)
      for (int ni = 0; ni < 4; ni++) {
        const int col = colBase + wc + ni * 16 + lr;
        const int row0 = rowBase + wr + mi * 16 + lq * 4;
        for (int r = 0; r < 4; r++)
          qb[(size_t)(row0 + r) * HDIM + col] = (bf16)acc[mi][ni][r];
      }
  } else if (z == 1) {
    for (int mi = 0; mi < 4; mi++)
      for (int ni = 0; ni < 4; ni++) {
        const int dim = colBase + wc + ni * 16 + lr;
        const int hh = dim >> 7, ks = (dim >> 5) & 3, kh = (dim >> 3) & 3, j = dim & 7;
        const int row0 = rowBase + wr + mi * 16 + lq * 4;
        for (int r = 0; r < 4; r++) {
          const int key = row0 + r;
          const int kbk = key >> 7, kni = (key >> 4) & 7, kl = key & 15;
          Kf[(((size_t)hh * 16 + kbk) * 32 + kni * 4 + ks) * 512 +
             (kh * 16 + kl) * 8 + j] = (bf16)acc[mi][ni][r];
        }
      }
  } else {
    for (int mi = 0; mi < 4; mi++)
      for (int ni = 0; ni < 4; ni++) {
        const int dim = colBase + wc + ni * 16 + lr;
        const int hh = dim >> 7, vni = (dim >> 4) & 7, ll = dim & 15;
        const int row0 = rowBase + wr + mi * 16 + lq * 4;
        const int kbk = row0 >> 7, ks = (row0 >> 5) & 3, lh = (row0 >> 3) & 3;
        const int j0 = row0 & 7;  // r=0..3 contiguous in j
        union { bf16 h4[4]; s16x4 v; } u;
        for (int r = 0; r < 4; r++) u.h4[r] = (bf16)acc[mi][ni][r];
        *(s16x4*)&Vf[(((size_t)hh * 16 + kbk) * 32 + vni * 4 + ks) * 512 +
                     (lh * 16 + ll) * 8 + j0] = u.v;
      }
  }
}

// Flash attention v6: 4 waves = 2(q-half:32 rows) x 2(key-half:64 keys).
// S computed TRANSPOSED (A=K,B=Q -> lanes hold 4 consecutive keys) so P
// writes are b64; b128 reads halve per wave via key split. Streaming softmax;
// O/lsum combined across key-half waves once at the end (additive).
__global__ __launch_bounds__(256, 2) void attn_kernel(
    const bf16* __restrict__ qb, const bf16* __restrict__ Kf,
    const bf16* __restrict__ Vf, const unsigned char* __restrict__ amask,
    bf16* __restrict__ ctx) {
  __shared__ bf16 Kl[32 * 512];     // K frag tile (32KB); reused as O-combine
  __shared__ bf16 Vl[32 * 512];     // V frag tile (32KB); reused for lsums
  __shared__ bf16 Pl[4 * 2048];     // per-wave P: 32 rows x 64 keys (16KB)

  const int qt = blockIdx.x, h = blockIdx.y;
  const int t = threadIdx.x, w = t >> 6, l = t & 63;
  const int lr = l & 15, lq = l >> 4;
  const int wq = w & 1, wk = w >> 1;
  bf16* Pw = Pl + (w << 11);

  // Q B-frags (registers, once): B[n=qrow][k=dim]
  bf16x8 aq[2][4];
  for (int mi = 0; mi < 2; mi++)
    for (int ks = 0; ks < 4; ks++)
      aq[mi][ks] = *(const bf16x8*)&qb[(size_t)(qt * 64 + wq * 32 + mi * 16 + lr) * HDIM +
                                       h * 128 + ks * 32 + lq * 8];

  f32x4 o[2][8];
  for (int mi = 0; mi < 2; mi++)
    for (int ni = 0; ni < 8; ni++)
      for (int r = 0; r < 4; r++) o[mi][ni][r] = 0.f;
  float lsum[2] = {0.f, 0.f};

  const float c = 0.08838834764831845f * 1.4426950408889634f;  // 1/sqrt(128)*log2e
  const int lr7 = lr & 7;

  for (int kbk = 0; kbk < 16; kbk++) {
    const size_t tileOff = ((size_t)h * 16 + kbk) * 32 * 512;

    // stage K via glds16 (8, single dest — proven depth)
    for (int i = 0; i < 8; i++) {
      const int frag = i * 4 + w;
      glds16(Kf + tileOff + frag * 512 + l * 8, Kl + frag * 512);
    }
    // stage V via regs + ds_write_b128
    bf16x8 vtmp[8];
    for (int i = 0; i < 8; i++)
      vtmp[i] = *(const bf16x8*)&Vf[tileOff + (i * 4 + w) * 512 + l * 8];
    for (int i = 0; i < 8; i++)
      *(bf16x8*)&Vl[(i * 4 + w) * 512 + l * 8] = vtmp[i];
    __syncthreads();

    // S^T = K @ Q^T : s[mi][ni] D[m=key][n=qrow]; wave's keys = wk*64..+64
    f32x4 s[2][4];
    for (int mi = 0; mi < 2; mi++)
      for (int ni = 0; ni < 4; ni++)
        for (int r = 0; r < 4; r++) s[mi][ni][r] = 0.f;
    for (int ks = 0; ks < 4; ks++) {
      bf16x8 bk[4];
      for (int ni = 0; ni < 4; ni++)
        bk[ni] = *(const bf16x8*)&Kl[((wk * 4 + ni) * 4 + ks) * 512 + l * 8];
      for (int mi = 0; mi < 2; mi++)
        for (int ni = 0; ni < 4; ni++)
          s[mi][ni] = MFMA16(bk[ni], aq[mi][ks], s[mi][ni]);
    }

    // mask + exp + lsum partials. lane: key = kbase+r, qrow = qt*64+wq*32+mi*16+lr
    const bool dblk = (((kbk << 1) | wk) == qt);
    for (int ni = 0; ni < 4; ni++) {
      const int kbase = kbk * 128 + wk * 64 + ni * 16 + lq * 4;
      const unsigned mword = *(const unsigned*)&amask[kbase];
      for (int mi = 0; mi < 2; mi++) {
        const int qrowg = qt * 64 + wq * 32 + mi * 16 + lr;
        for (int r = 0; r < 4; r++) {
          float p = __builtin_exp2f(s[mi][ni][r] * c);
          if (!((mword >> (8 * r)) & 0xffu)) p = 0.f;
          if (dblk && (kbase + r == qrowg)) p = 0.f;
          s[mi][ni][r] = p;
          lsum[mi] += p;
        }
      }
    }

    // P -> LDS: row = mi*16+lr, local keys ni*16+lq*4..+3; XOR-swizzled 8-groups
    for (int mi = 0; mi < 2; mi++)
      for (int ni = 0; ni < 4; ni++) {
        union { bf16 h4[4]; s16x4 v; } u;
        for (int r = 0; r < 4; r++) u.h4[r] = (bf16)s[mi][ni][r];
        const int row = mi * 16 + lr;
        const int g = ((ni * 2 + (lq >> 1)) ^ lr7);
        *(s16x4*)&Pw[row * 64 + (g << 3) + ((lq & 1) << 2)] = u.v;
      }

    // O += P @ V  (wave's key-half: V frags ks_key = wk*2 + ks2)
    for (int ks2 = 0; ks2 < 2; ks2++) {
      bf16x8 ap[2];
      for (int mi = 0; mi < 2; mi++)
        ap[mi] = *(const bf16x8*)&Pw[(mi * 16 + lr) * 64 +
                                     (((ks2 * 4 + lq) ^ lr7) << 3)];
      for (int ni = 0; ni < 8; ni++) {
        const bf16x8 bv = *(const bf16x8*)&Vl[(ni * 4 + wk * 2 + ks2) * 512 + l * 8];
        for (int mi = 0; mi < 2; mi++)
          o[mi][ni] = MFMA16(ap[mi], bv, o[mi][ni]);
      }
    }
    __syncthreads();
  }

  // reduce lsum over lq (lanes xor 16/32 share qrow=lr)
  for (int mi = 0; mi < 2; mi++) {
    lsum[mi] += __shfl_xor(lsum[mi], 16);
    lsum[mi] += __shfl_xor(lsum[mi], 32);
  }

  // cross-key-half combine through dead K/V LDS
  float* Ocomb = (float*)Kl;              // 2 x 16KB regions
  float* Ls = (float*)Vl;                 // [0..63] halves, [64..127] final
  if (wk == 1) {
    f32x4* dst = (f32x4*)Ocomb + wq * 1024;
    for (int i = 0; i < 16; i++) dst[i * 64 + l] = o[i >> 3][i & 7];
    if (lq == 0) {
      Ls[wq * 32 + lr] = lsum[0];
      Ls[wq * 32 + 16 + lr] = lsum[1];
    }
  }
  __syncthreads();
  if (wk == 0) {
    const f32x4* src = (const f32x4*)Ocomb + wq * 1024;
    for (int i = 0; i < 16; i++) {
      const f32x4 v = src[i * 64 + l];
      for (int r = 0; r < 4; r++) o[i >> 3][i & 7][r] += v[r];
    }
    lsum[0] += Ls[wq * 32 + lr];
    lsum[1] += Ls[wq * 32 + 16 + lr];
    Ls[64 + wq * 32 + lr] = lsum[0];        // all lq write same value
    Ls[64 + wq * 32 + 16 + lr] = lsum[1];
  }
  __syncthreads();
  if (wk == 0) {
    // O C-layout: row-local = mi*16 + lq*4 + r, dim = ni*16 + lr
    for (int mi = 0; mi < 2; mi++)
      for (int r = 0; r < 4; r++) {
        const float li = Ls[64 + wq * 32 + mi * 16 + lq * 4 + r];
        const int row = qt * 64 + wq * 32 + mi * 16 + lq * 4 + r;
        for (int ni = 0; ni < 8; ni++) {
          const float val = (li > 0.f) ? o[mi][ni][r] / li : 0.f;
          ctx[(size_t)row * HDIM + h * 128 + ni * 16 + lr] = (bf16)val;
        }
      }
  }
}

// out = fp32( hs + sigmoid(scale) * (ctx @ Wo^T) ), 128x64 tiles, frag-major.
__global__ __launch_bounds__(256) void out_gemm(
    const bf16* __restrict__ ctx, const bf16* __restrict__ Wo,
    const float* __restrict__ hs, const float* __restrict__ scale_p,
    float* __restrict__ outp) {
  __shared__ bf16 ldsA[128 * 32];
  __shared__ bf16 ldsB[64 * 32];
  const int rowBase = blockIdx.y << 7, colBase = blockIdx.x << 6;
  const int t = threadIdx.x;
  const int w = t >> 6, l = t & 63;
  const int wr = (w >> 1) << 6, wc = (w & 1) << 5;
  const int lr = l & 15, lq = l >> 4;

  f32x4 acc[4][2];
  for (int mi = 0; mi < 4; mi++)
    for (int ni = 0; ni < 2; ni++)
      for (int r = 0; r < 4; r++) acc[mi][ni][r] = 0.f;

  const int fr = l & 15;
  const int fc = (l >> 4) << 3;
  const bf16* gA0 = ctx + (size_t)(rowBase + w * 32 + fr) * HDIM + fc;
  const bf16* gA1 = gA0 + (size_t)16 * HDIM;
  const bf16* gB0 = Wo + (size_t)(colBase + w * 16 + fr) * HDIM + fc;
  bf16* lA = ldsA + (w << 10);
  bf16* lB = ldsB + (w << 9);

  const int af0 = (w >> 1) << 2;
  const int bf0 = (w & 1) << 1;

  for (int k0 = 0; k0 < HDIM; k0 += 32) {
    glds16(gA0, lA);
    glds16(gA1, lA + 512);
    glds16(gB0, lB);
    gA0 += 32; gA1 += 32; gB0 += 32;
    __syncthreads();

    bf16x8 af[4], bfr[2];
    for (int mi = 0; mi < 4; mi++)
      af[mi] = *(const bf16x8*)&ldsA[(af0 + mi) * 512 + l * 8];
    for (int ni = 0; ni < 2; ni++)
      bfr[ni] = *(const bf16x8*)&ldsB[(bf0 + ni) * 512 + l * 8];
    for (int mi = 0; mi < 4; mi++)
      for (int ni = 0; ni < 2; ni++)
        acc[mi][ni] = MFMA16(af[mi], bfr[ni], acc[mi][ni]);
    __syncthreads();
  }

  const float sig = 1.0f / (1.0f + __expf(-scale_p[0]));
  for (int mi = 0; mi < 4; mi++)
    for (int ni = 0; ni < 2; ni++) {
      const int col = colBase + wc + ni * 16 + lr;
      const int row0 = rowBase + wr + mi * 16 + lq * 4;
      for (int r = 0; r < 4; r++) {
        const size_t idx = (size_t)(row0 + r) * HDIM + col;
        outp[idx] = hs[idx] + sig * acc[mi][ni][r];
      }
    }
}

extern "C" void kernel_launch(void* const* d_in, const int* in_sizes, int n_in,
                              void* d_out, int out_size, void* d_ws, size_t ws_size,
                              hipStream_t stream) {
  const float* hs = (const float*)d_in[0];
  const unsigned char* amask = (const unsigned char*)d_in[1];
  const float* Wq = (const float*)d_in[2];
  const float* Wk = (const float*)d_in[3];
  const float* Wv = (const float*)d_in[4];
  const float* Wo = (const float*)d_in[5];
  const float* scale_p = (const float*)d_in[6];
  float* outp = (float*)d_out;

  const size_t N = (size_t)HDIM * HDIM;
  bf16* qb   = (bf16*)d_ws;
  bf16* Kf   = qb + N;
  bf16* Vf   = Kf + N;
  bf16* ctx  = Vf + N;
  bf16* hs16 = ctx + N;
  bf16* Wq16 = hs16 + N;
  bf16* Wk16 = Wq16 + N;
  bf16* Wv16 = Wk16 + N;
  bf16* Wo16 = Wv16 + N;   // 72 MB of d_ws

  cvt5<<<dim3(1024, 5), 256, 0, stream>>>(hs, Wq, Wk, Wv, Wo,
                                          hs16, Wq16, Wk16, Wv16, Wo16);
  qkv_gemm<<<dim3(16, 16, 3), 256, 0, stream>>>(hs16, Wq16, Wk16, Wv16, qb, Kf, Vf);
  attn_kernel<<<dim3(32, 16), 256, 0, stream>>>(qb, Kf, Vf, amask, ctx);
  out_gemm<<<dim3(32, 16), 256, 0, stream>>>(ctx, Wo16, hs, scale_p, outp);
}